// Round 9
// baseline (134.317 us; speedup 1.0000x reference)
//
#include <hip/hip_runtime.h>
#include <hip/hip_bf16.h>

#define N_ROWS 8192
#define H_DIM  1024
#define NUM_CLS 64
#define BM 128
#define BN 128
#define BK 128                           // K per step (one scaled MFMA)
#define NBLK (N_ROWS / BM)               // 64 panels
#define SCALE_E8M0 0x7B7B7B7B            // 123 -> 2^-4 per operand (x stored *16)
#define FIXSCALE 16777216.0              // 2^24 fixed-point for deterministic sum
#define GRID_K2 (8 * 264)                // 8 XCD slots x 264 (32 no-op blocks)

typedef float f32x4 __attribute__((ext_vector_type(4)));
typedef int   i32x4 __attribute__((ext_vector_type(4)));
typedef int   i32x8 __attribute__((ext_vector_type(8)));

__device__ __forceinline__ float fast_exp2(float x) {
    float r;
    asm("v_exp_f32 %0, %1" : "=v"(r) : "v"(x));
    return r;
}

__device__ __forceinline__ void async_copy16(void* lds, const void* g) {
    __builtin_amdgcn_global_load_lds(
        (const __attribute__((address_space(1))) void*)g,
        (__attribute__((address_space(3))) void*)lds, 16, 0, 0);
}

// ------- Kernel 1: row-normalize fp32 -> fp8 e4m3 (x*16); 4 rows/block -------
__global__ __launch_bounds__(256) void norm_kernel(const float* __restrict__ in,
                                                   int* __restrict__ out,
                                                   unsigned long long* __restrict__ acc) {
    if (blockIdx.x == 0 && threadIdx.x < 4) acc[threadIdx.x] = 0ULL;  // zero reducers
    const int row  = blockIdx.x * 4 + (threadIdx.x >> 6);
    const int lane = threadIdx.x & 63;
    const float4* src = reinterpret_cast<const float4*>(in + (size_t)row * H_DIM);
    float4 v[4];
    float ss = 0.f;
#pragma unroll
    for (int i = 0; i < 4; ++i) {
        v[i] = src[i * 64 + lane];                    // coalesced 16B/lane
        ss += v[i].x * v[i].x + v[i].y * v[i].y + v[i].z * v[i].z + v[i].w * v[i].w;
    }
#pragma unroll
    for (int d = 1; d < 64; d <<= 1) ss += __shfl_xor(ss, d, 64);
    const float inv = 16.0f / fmaxf(sqrtf(ss), 1e-12f);   // *16: e4m3 normal range
    int* op = out + (size_t)row * (H_DIM / 4);
#pragma unroll
    for (int i = 0; i < 4; ++i) {
        int d = 0;
        d = __builtin_amdgcn_cvt_pk_fp8_f32(v[i].x * inv, v[i].y * inv, d, false);
        d = __builtin_amdgcn_cvt_pk_fp8_f32(v[i].z * inv, v[i].w * inv, d, true);
        op[i * 64 + lane] = d;
    }
}

// 28 off-diagonal 8x8-panel super-tiles (a<b), packed a<<3|b, row-major
__device__ __constant__ unsigned char OFF_TBL[28] = {
    1, 2, 3, 4, 5, 6, 7,
    10, 11, 12, 13, 14, 15,
    19, 20, 21, 22, 23,
    28, 29, 30, 31,
    37, 38, 39,
    46, 47,
    55
};

// ---- Kernel 2: symmetric fused Gram + exp + masked row/col partials ----
// A-fragments loaded DIRECT from global (L1/L2-hot via super-tile co-schedule);
// only B goes through LDS (double-buffered, 32 KB total). One barrier/step.
__global__ __launch_bounds__(256, 3)
void simloss_kernel(const unsigned char* __restrict__ xq, const int* __restrict__ labels,
                    float* __restrict__ ppos, float* __restrict__ pall) {
    __shared__ __align__(16) unsigned char Bs[2 * BN * BK];   // 2 x 16 KB

    // ---- super-tile decode: xcd = blockIdx%8 owns a fixed tile list ----
    const int xcd = blockIdx.x & 7;
    const int n   = blockIdx.x >> 3;     // 0..263 within this XCD
    int I, J;
    if (xcd < 4) {                        // 4 off-diag tiles (256 blocks)
        if (n >= 256) return;
        const int t = OFF_TBL[xcd * 4 + (n >> 6)];
        I = (t >> 3) * 8 + ((n >> 3) & 7);
        J = (t & 7) * 8 + (n & 7);
    } else if (n < 192) {                 // 3 off-diag tiles
        const int t = OFF_TBL[16 + (xcd - 4) * 3 + (n >> 6)];
        I = (t >> 3) * 8 + ((n >> 3) & 7);
        J = (t & 7) * 8 + (n & 7);
    } else {                              // 2 diag tiles (36 blocks each)
        int n2 = n - 192;                 // 0..71
        const int D = (xcd - 4) * 2 + (n2 >= 36 ? 1 : 0);
        int t2 = (n2 >= 36) ? n2 - 36 : n2;
        int i = 0;
        while (t2 >= 8 - i) { t2 -= 8 - i; ++i; }
        I = D * 8 + i;
        J = D * 8 + i + t2;
    }
    const bool diag = (I == J);
    const int row0 = I * BM, col0 = J * BN;

    const int tid  = threadIdx.x;
    const int lane = tid & 63;
    const int wid  = tid >> 6;
    const int wr = wid >> 1, wc = wid & 1;
    const int l15 = lane & 15, lq = lane >> 4;
    const int l7 = l15 & 7;

    // staging geometry: segment = 1 KB = 8 rows x 128 B; 16 segs per B tile
    const int srow  = lane >> 3;   // row within segment (0..7)
    const int pslot = lane & 7;    // physical 16B slot within row

    f32x4 acc[4][4];
#pragma unroll
    for (int m = 0; m < 4; ++m)
#pragma unroll
        for (int n2 = 0; n2 < 4; ++n2) acc[m][n2] = (f32x4){0.f, 0.f, 0.f, 0.f};

    // B fragment reads: logical K-chunks 2lq,2lq+1 live at physical slots
    // lq^row7 and (4+lq)^row7 (measured zero-conflict families)
    const int s0 = (lq ^ l7) * 16;
    const int s1 = ((4 + lq) ^ l7) * 16;

    // A direct-load base: lane (l15,lq) reads row (wr*64 + m*16 + l15),
    // bytes [k0 + lq*32, +32) -- 4 lanes cover each 128B row chunk (L1-hot)
    const unsigned char* Abase = xq + (size_t)(row0 + wr * 64 + l15) * H_DIM + lq * 32;

#define STAGE_B(buf, k0)                                                       \
    do {                                                                       \
        _Pragma("unroll")                                                      \
        for (int q = 0; q < 4; ++q) {                                          \
            const int seg = wid * 4 + q;                                       \
            const int row = seg * 8 + srow;                                    \
            const int p   = pslot ^ (row & 7);                                 \
            const int ls  = ((p & 3) << 1) | (p >> 2);                         \
            async_copy16(&Bs[(buf) * 16384 + seg * 1024],                      \
                         &xq[(size_t)(col0 + row) * H_DIM + (k0) + ls * 16]);  \
        }                                                                      \
    } while (0)

    // prologue: stage B(0) into buf 0
    STAGE_B(0, 0);
    __syncthreads();

    for (int k0 = 0; k0 < H_DIM; k0 += BK) {
        const int buf = (k0 >> 7) & 1;
        if (k0 + BK < H_DIM) STAGE_B(buf ^ 1, k0 + BK);   // async, other buffer

        i32x8 av[4], bv[4];
#pragma unroll
        for (int m = 0; m < 4; ++m) {
            const unsigned char* ap = Abase + (size_t)m * 16 * H_DIM + k0;
            const i32x4 lo = *reinterpret_cast<const i32x4*>(ap);
            const i32x4 hi = *reinterpret_cast<const i32x4*>(ap + 16);
            av[m] = __builtin_shufflevector(lo, hi, 0, 1, 2, 3, 4, 5, 6, 7);
        }
#pragma unroll
        for (int n2 = 0; n2 < 4; ++n2) {
            const int base = buf * 16384 + (wc * 64 + n2 * 16 + l15) * BK;
            const i32x4 lo = *reinterpret_cast<const i32x4*>(&Bs[base + s0]);
            const i32x4 hi = *reinterpret_cast<const i32x4*>(&Bs[base + s1]);
            bv[n2] = __builtin_shufflevector(lo, hi, 0, 1, 2, 3, 4, 5, 6, 7);
        }
#pragma unroll
        for (int m = 0; m < 4; ++m)
#pragma unroll
            for (int n2 = 0; n2 < 4; ++n2)
                acc[m][n2] = __builtin_amdgcn_mfma_scale_f32_16x16x128_f8f6f4(
                    av[m], bv[n2], acc[m][n2],
                    0 /*cbsz: fp8 e4m3*/, 0 /*blgp: fp8 e4m3*/,
                    0, SCALE_E8M0, 0, SCALE_E8M0);

        // drains stage(t+1) (issued ~700 cyc ago) + fences buffer swap
        __syncthreads();
    }
#undef STAGE_B

    // ---- epilogue: exp + masked row sums AND column sums ----
    int lab_r[16];                         // loaded here: not loop-live
#pragma unroll
    for (int m = 0; m < 4; ++m)
#pragma unroll
        for (int r = 0; r < 4; ++r)
            lab_r[m * 4 + r] = labels[row0 + wr * 64 + m * 16 + lq * 4 + r];

    float rs_pos[16], rs_all[16];
#pragma unroll
    for (int i = 0; i < 16; ++i) { rs_pos[i] = 0.f; rs_all[i] = 0.f; }
    float cs_pos[4], cs_all[4];
#pragma unroll
    for (int n2 = 0; n2 < 4; ++n2) { cs_pos[n2] = 0.f; cs_all[n2] = 0.f; }

#pragma unroll
    for (int n2 = 0; n2 < 4; ++n2) {
        const int colg = col0 + wc * 64 + n2 * 16 + l15;
        const int lab_c = labels[colg];
#pragma unroll
        for (int m = 0; m < 4; ++m) {
#pragma unroll
            for (int r = 0; r < 4; ++r) {
                const int rowg = row0 + wr * 64 + m * 16 + lq * 4 + r;
                const float e = fast_exp2(acc[m][n2][r] * 14.4269504088896340736f);
                const bool self = (rowg == colg);       // only possible when diag
                const bool pos  = (lab_c == lab_r[m * 4 + r]) && !self;
                const float ea = self ? 0.f : e;
                const float ep = pos ? e : 0.f;
                rs_all[m * 4 + r] += ea;
                rs_pos[m * 4 + r] += ep;
                cs_all[n2] += ea;
                cs_pos[n2] += ep;
            }
        }
    }

#pragma unroll
    for (int i = 0; i < 16; ++i) {
#pragma unroll
        for (int d = 1; d < 16; d <<= 1) {
            rs_pos[i] += __shfl_xor(rs_pos[i], d, 64);
            rs_all[i] += __shfl_xor(rs_all[i], d, 64);
        }
    }
#pragma unroll
    for (int n2 = 0; n2 < 4; ++n2) {
#pragma unroll
        for (int d = 16; d < 64; d <<= 1) {
            cs_pos[n2] += __shfl_xor(cs_pos[n2], d, 64);
            cs_all[n2] += __shfl_xor(cs_all[n2], d, 64);
        }
    }

    __syncthreads();                       // all LDS reads done; reuse as scratch
    float* sc = (float*)&Bs[0];
    float* rowpos = sc;                    // [2][128] indexed [wc][localrow]
    float* rowall = sc + 256;
    float* colpos = sc + 512;              // [2][128] indexed [wr][localcol]
    float* colall = sc + 768;
    if (l15 == 0) {
#pragma unroll
        for (int i = 0; i < 16; ++i) {
            const int m = i >> 2, r = i & 3;
            const int lr = wr * 64 + m * 16 + lq * 4 + r;
            rowpos[wc * 128 + lr] = rs_pos[i];
            rowall[wc * 128 + lr] = rs_all[i];
        }
    }
    if (lq == 0 && !diag) {
#pragma unroll
        for (int n2 = 0; n2 < 4; ++n2) {
            const int lc = wc * 64 + n2 * 16 + l15;
            colpos[wr * 128 + lc] = cs_pos[n2];
            colall[wr * 128 + lc] = cs_all[n2];
        }
    }
    __syncthreads();

    // partial-slot scheme: row-side -> slot J, col-side -> slot I (exactly once)
    if (tid < 128) {
        const float rp = rowpos[tid] + rowpos[128 + tid];
        const float ra = rowall[tid] + rowall[128 + tid];
        ppos[(size_t)J * N_ROWS + row0 + tid] = rp;
        pall[(size_t)J * N_ROWS + row0 + tid] = ra;
    } else if (!diag) {
        const int t2 = tid - 128;
        const float cp = colpos[t2] + colpos[128 + t2];
        const float ca = colall[t2] + colall[128 + t2];
        ppos[(size_t)I * N_ROWS + col0 + t2] = cp;
        pall[(size_t)I * N_ROWS + col0 + t2] = ca;
    }
}

// ---- Kernel 3: fused finalize (deterministic int64 fixed-point + ticket) ----
__global__ __launch_bounds__(256)
void finalize_kernel(const int* __restrict__ labels, const float* __restrict__ ppos,
                     const float* __restrict__ pall, unsigned long long* __restrict__ acc,
                     float* __restrict__ out) {
    __shared__ int hist[NUM_CLS];
    __shared__ float sred[4];
    __shared__ int scnt[4];
    const int tid = threadIdx.x;
    if (tid < NUM_CLS) hist[tid] = 0;
    __syncthreads();
    for (int i = tid; i < N_ROWS; i += 256) atomicAdd(&hist[labels[i]], 1);
    __syncthreads();

    float lsum = 0.f;
    int vcnt = 0;
    if (tid < 128) {
        const int i = blockIdx.x * 128 + tid;
        float p = 0.f, a = 0.f;
#pragma unroll
        for (int s = 0; s < NBLK; ++s) {
            p += ppos[(size_t)s * N_ROWS + i];
            a += pall[(size_t)s * N_ROWS + i];
        }
        const int cnt = hist[labels[i]] - 1;
        if (cnt > 0) {
            lsum = logf(a) - logf(p) + logf((float)cnt);   // >= 0 structurally
            vcnt = 1;
        }
    }
    const int lane = tid & 63, wid = tid >> 6;
#pragma unroll
    for (int d = 1; d < 64; d <<= 1) {
        lsum += __shfl_xor(lsum, d, 64);
        vcnt += __shfl_xor(vcnt, d, 64);
    }
    if (lane == 0) { sred[wid] = lsum; scnt[wid] = vcnt; }
    __syncthreads();
    if (tid == 0) {
        const double bs = (double)(sred[0] + sred[1] + sred[2] + sred[3]);
        const unsigned long long S = (unsigned long long)(bs * FIXSCALE + 0.5);
        const unsigned long long C = (unsigned long long)(scnt[0] + scnt[1] + scnt[2] + scnt[3]);
        atomicAdd(&acc[1], S);
        atomicAdd(&acc[2], C);
        __threadfence();
        const unsigned long long tk = atomicAdd(&acc[0], 1ULL);
        if (tk == (unsigned long long)(NBLK - 1)) {
            volatile unsigned long long* va = acc;
            const double St = (double)va[1];
            const double Ct = (double)va[2];
            out[0] = (float)(St / FIXSCALE / Ct);
        }
    }
}

extern "C" void kernel_launch(void* const* d_in, const int* in_sizes, int n_in,
                              void* d_out, int out_size, void* d_ws, size_t ws_size,
                              hipStream_t stream) {
    const float* emb   = (const float*)d_in[0];
    const int* labels  = (const int*)d_in[1];
    float* out         = (float*)d_out;
    char* ws           = (char*)d_ws;

    unsigned char* xq = (unsigned char*)ws;                      // 8 MB fp8 (x*16)
    float* ppos = (float*)(ws + (size_t)N_ROWS * H_DIM);         // NBLK*N floats (2 MB)
    float* pall = ppos + (size_t)NBLK * N_ROWS;                  // NBLK*N floats (2 MB)
    unsigned long long* acc = (unsigned long long*)(pall + (size_t)NBLK * N_ROWS);

    norm_kernel<<<N_ROWS / 4, 256, 0, stream>>>(emb, (int*)xq, acc);
    simloss_kernel<<<GRID_K2, 256, 0, stream>>>(xq, labels, ppos, pall);
    finalize_kernel<<<NBLK, 256, 0, stream>>>(labels, ppos, pall, acc, out);
}

// Round 10
// 93.049 us; speedup vs baseline: 1.4435x; 1.4435x over previous
//
#include <hip/hip_runtime.h>
#include <hip/hip_bf16.h>

#define N_ROWS 8192
#define H_DIM  1024
#define NUM_CLS 64
#define BM 128
#define BN 128
#define BK 128                           // K elems per step (one scaled MFMA)
#define ROWB (H_DIM / 2)                 // 512 bytes per fp4 row
#define NBLK (N_ROWS / BM)               // 64 panels
#define SCALE_E8M0 0x79797979            // 121 -> 2^-6 per operand (x stored *64)
#define FIXSCALE 16777216.0              // 2^24 fixed-point for deterministic sum
#define GRID_K2 (8 * 264)                // 8 XCD slots x 264 (32 no-op blocks)

typedef float f32x4 __attribute__((ext_vector_type(4)));
typedef int   i32x4 __attribute__((ext_vector_type(4)));
typedef int   i32x8 __attribute__((ext_vector_type(8)));

__device__ __forceinline__ float fast_exp2(float x) {
    float r;
    asm("v_exp_f32 %0, %1" : "=v"(r) : "v"(x));
    return r;
}

__device__ __forceinline__ void async_copy16(void* lds, const void* g) {
    __builtin_amdgcn_global_load_lds(
        (const __attribute__((address_space(1))) void*)g,
        (__attribute__((address_space(3))) void*)lds, 16, 0, 0);
}

// e2m1 encode of f (pre-scaled): codes 0..7 = {0,.5,1,1.5,2,3,4,6}, bit3 = sign
__device__ __forceinline__ unsigned enc_fp4(float f) {
    const float a = fabsf(f);
    unsigned c = (unsigned)(a > 0.25f) + (unsigned)(a > 0.75f) +
                 (unsigned)(a > 1.25f) + (unsigned)(a > 1.75f) +
                 (unsigned)(a > 2.5f)  + (unsigned)(a > 3.5f) +
                 (unsigned)(a > 5.0f);
    return c | ((__float_as_uint(f) >> 31) << 3);
}

// --- Kernel 1: row-normalize fp32 -> fp4 e2m1 (x*64); 4 rows/block ---
__global__ __launch_bounds__(256) void norm_kernel(const float* __restrict__ in,
                                                   ushort* __restrict__ out,
                                                   unsigned long long* __restrict__ acc) {
    if (blockIdx.x == 0 && threadIdx.x < 4) acc[threadIdx.x] = 0ULL;  // zero reducers
    const int row  = blockIdx.x * 4 + (threadIdx.x >> 6);
    const int lane = threadIdx.x & 63;
    const float4* src = reinterpret_cast<const float4*>(in + (size_t)row * H_DIM);
    float4 v[4];
    float ss = 0.f;
#pragma unroll
    for (int i = 0; i < 4; ++i) {
        v[i] = src[i * 64 + lane];                    // coalesced 16B/lane
        ss += v[i].x * v[i].x + v[i].y * v[i].y + v[i].z * v[i].z + v[i].w * v[i].w;
    }
#pragma unroll
    for (int d = 1; d < 64; d <<= 1) ss += __shfl_xor(ss, d, 64);
    const float inv = 64.0f / fmaxf(sqrtf(ss), 1e-12f);   // *64: fp4 resolution band
    ushort* op = out + (size_t)row * (ROWB / 2);          // 256 ushorts per row
#pragma unroll
    for (int i = 0; i < 4; ++i) {
        // elems i*256 + lane*4 .. +4 -> 2 bytes at byte (i*128 + lane*2)
        const unsigned b0 = enc_fp4(v[i].x * inv) | (enc_fp4(v[i].y * inv) << 4);
        const unsigned b1 = enc_fp4(v[i].z * inv) | (enc_fp4(v[i].w * inv) << 4);
        op[i * 64 + lane] = (ushort)(b0 | (b1 << 8));
    }
}

// 28 off-diagonal 8x8-panel super-tiles (a<b), packed a<<3|b, row-major
__device__ __constant__ unsigned char OFF_TBL[28] = {
    1, 2, 3, 4, 5, 6, 7,
    10, 11, 12, 13, 14, 15,
    19, 20, 21, 22, 23,
    28, 29, 30, 31,
    37, 38, 39,
    46, 47,
    55
};

// ---- Kernel 2: symmetric fused Gram + exp + masked row/col partials ----
// R8 structure, MX-fp4: tile 128x64B, LDS 16 KB, stage 4 issues/thread/step,
// reads 1x ds_read_b128 per fragment (zero-conflict XOR family), 4 blocks/CU.
__global__ __launch_bounds__(256, 4)
void simloss_kernel(const unsigned char* __restrict__ xq, const int* __restrict__ labels,
                    float* __restrict__ ppos, float* __restrict__ pall) {
    __shared__ __align__(16) unsigned char As[BM * 64];   // 8 KB
    __shared__ __align__(16) unsigned char Bs[BN * 64];   // 8 KB

    // ---- super-tile decode: xcd = blockIdx%8 owns a fixed tile list ----
    const int xcd = blockIdx.x & 7;
    const int n   = blockIdx.x >> 3;     // 0..263 within this XCD
    int I, J;
    if (xcd < 4) {                        // 4 off-diag tiles (256 blocks)
        if (n >= 256) return;
        const int t = OFF_TBL[xcd * 4 + (n >> 6)];
        I = (t >> 3) * 8 + ((n >> 3) & 7);
        J = (t & 7) * 8 + (n & 7);
    } else if (n < 192) {                 // 3 off-diag tiles
        const int t = OFF_TBL[16 + (xcd - 4) * 3 + (n >> 6)];
        I = (t >> 3) * 8 + ((n >> 3) & 7);
        J = (t & 7) * 8 + (n & 7);
    } else {                              // 2 diag tiles (36 blocks each)
        int n2 = n - 192;                 // 0..71
        const int D = (xcd - 4) * 2 + (n2 >= 36 ? 1 : 0);
        int t2 = (n2 >= 36) ? n2 - 36 : n2;
        int i = 0;
        while (t2 >= 8 - i) { t2 -= 8 - i; ++i; }
        I = D * 8 + i;
        J = D * 8 + i + t2;
    }
    const bool diag = (I == J);
    const int row0 = I * BM, col0 = J * BN;

    const int tid  = threadIdx.x;
    const int lane = tid & 63;
    const int wid  = tid >> 6;
    const int wr = wid >> 1, wc = wid & 1;
    const int l15 = lane & 15, lq = lane >> 4;

    f32x4 acc[4][4];
#pragma unroll
    for (int m = 0; m < 4; ++m)
#pragma unroll
        for (int n2 = 0; n2 < 4; ++n2) acc[m][n2] = (f32x4){0.f, 0.f, 0.f, 0.f};

    // fragment read slot: lane needs K [lq*32,+32) = 16B at phys slot lq^(row&3)
    const int rslot = (lq ^ (l15 & 3)) * 16;
    const i32x4 z4 = {0, 0, 0, 0};

    for (int k0b = 0; k0b < ROWB; k0b += 64) {       // 8 steps, 64 B of K each
        __syncthreads();   // previous step's LDS reads complete
#pragma unroll
        for (int q = 0; q < 2; ++q) {
            // seg = 16 rows x 64 B = 1 KB; lane covers row seg*16+(lane>>2),
            // slot lane&3, source pre-swizzled with the read's XOR (rule #21)
            const int seg = wid * 2 + q;
            const int row = seg * 16 + (lane >> 2);
            const int ls  = (lane & 3) ^ (row & 3);
            async_copy16(&As[seg * 1024],
                         &xq[(size_t)(row0 + row) * ROWB + k0b + ls * 16]);
            async_copy16(&Bs[seg * 1024],
                         &xq[(size_t)(col0 + row) * ROWB + k0b + ls * 16]);
        }
        __syncthreads();   // compiler drains vmcnt before s_barrier

        i32x8 av[4], bv[4];
#pragma unroll
        for (int m = 0; m < 4; ++m) {
            const i32x4 lo = *reinterpret_cast<const i32x4*>(
                &As[(wr * 64 + m * 16 + l15) * 64 + rslot]);
            av[m] = __builtin_shufflevector(lo, z4, 0, 1, 2, 3, 4, 5, 6, 7);
        }
#pragma unroll
        for (int n2 = 0; n2 < 4; ++n2) {
            const i32x4 lo = *reinterpret_cast<const i32x4*>(
                &Bs[(wc * 64 + n2 * 16 + l15) * 64 + rslot]);
            bv[n2] = __builtin_shufflevector(lo, z4, 0, 1, 2, 3, 4, 5, 6, 7);
        }
#pragma unroll
        for (int m = 0; m < 4; ++m)
#pragma unroll
            for (int n2 = 0; n2 < 4; ++n2)
                acc[m][n2] = __builtin_amdgcn_mfma_scale_f32_16x16x128_f8f6f4(
                    av[m], bv[n2], acc[m][n2],
                    4 /*cbsz: fp4 e2m1*/, 4 /*blgp: fp4 e2m1*/,
                    0, SCALE_E8M0, 0, SCALE_E8M0);
    }

    // ---- epilogue: exp + masked row sums AND column sums ----
    int lab_r[16];
#pragma unroll
    for (int m = 0; m < 4; ++m)
#pragma unroll
        for (int r = 0; r < 4; ++r)
            lab_r[m * 4 + r] = labels[row0 + wr * 64 + m * 16 + lq * 4 + r];

    float rs_pos[16], rs_all[16];
#pragma unroll
    for (int i = 0; i < 16; ++i) { rs_pos[i] = 0.f; rs_all[i] = 0.f; }
    float cs_pos[4], cs_all[4];
#pragma unroll
    for (int n2 = 0; n2 < 4; ++n2) { cs_pos[n2] = 0.f; cs_all[n2] = 0.f; }

#pragma unroll
    for (int n2 = 0; n2 < 4; ++n2) {
        const int colg = col0 + wc * 64 + n2 * 16 + l15;
        const int lab_c = labels[colg];
#pragma unroll
        for (int m = 0; m < 4; ++m) {
#pragma unroll
            for (int r = 0; r < 4; ++r) {
                const int rowg = row0 + wr * 64 + m * 16 + lq * 4 + r;
                const float e = fast_exp2(acc[m][n2][r] * 14.4269504088896340736f);
                const bool self = (rowg == colg);       // only possible when diag
                const bool pos  = (lab_c == lab_r[m * 4 + r]) && !self;
                const float ea = self ? 0.f : e;
                const float ep = pos ? e : 0.f;
                rs_all[m * 4 + r] += ea;
                rs_pos[m * 4 + r] += ep;
                cs_all[n2] += ea;
                cs_pos[n2] += ep;
            }
        }
    }

#pragma unroll
    for (int i = 0; i < 16; ++i) {
#pragma unroll
        for (int d = 1; d < 16; d <<= 1) {
            rs_pos[i] += __shfl_xor(rs_pos[i], d, 64);
            rs_all[i] += __shfl_xor(rs_all[i], d, 64);
        }
    }
#pragma unroll
    for (int n2 = 0; n2 < 4; ++n2) {
#pragma unroll
        for (int d = 16; d < 64; d <<= 1) {
            cs_pos[n2] += __shfl_xor(cs_pos[n2], d, 64);
            cs_all[n2] += __shfl_xor(cs_all[n2], d, 64);
        }
    }

    __syncthreads();                       // all LDS fragment reads done
    float* sc = (float*)&As[0];
    float* rowpos = sc;                    // [2][128] indexed [wc][localrow]
    float* rowall = sc + 256;
    float* colpos = sc + 512;              // [2][128] indexed [wr][localcol]
    float* colall = sc + 768;              // 4 KB total (As is 8 KB)
    if (l15 == 0) {
#pragma unroll
        for (int i = 0; i < 16; ++i) {
            const int m = i >> 2, r = i & 3;
            const int lr = wr * 64 + m * 16 + lq * 4 + r;
            rowpos[wc * 128 + lr] = rs_pos[i];
            rowall[wc * 128 + lr] = rs_all[i];
        }
    }
    if (lq == 0 && !diag) {
#pragma unroll
        for (int n2 = 0; n2 < 4; ++n2) {
            const int lc = wc * 64 + n2 * 16 + l15;
            colpos[wr * 128 + lc] = cs_pos[n2];
            colall[wr * 128 + lc] = cs_all[n2];
        }
    }
    __syncthreads();

    // partial-slot scheme: row-side -> slot J, col-side -> slot I (exactly once)
    if (tid < 128) {
        const float rp = rowpos[tid] + rowpos[128 + tid];
        const float ra = rowall[tid] + rowall[128 + tid];
        ppos[(size_t)J * N_ROWS + row0 + tid] = rp;
        pall[(size_t)J * N_ROWS + row0 + tid] = ra;
    } else if (!diag) {
        const int t2 = tid - 128;
        const float cp = colpos[t2] + colpos[128 + t2];
        const float ca = colall[t2] + colall[128 + t2];
        ppos[(size_t)I * N_ROWS + col0 + t2] = cp;
        pall[(size_t)I * N_ROWS + col0 + t2] = ca;
    }
}

// ---- Kernel 3: fused finalize (deterministic int64 fixed-point + ticket) ----
__global__ __launch_bounds__(256)
void finalize_kernel(const int* __restrict__ labels, const float* __restrict__ ppos,
                     const float* __restrict__ pall, unsigned long long* __restrict__ acc,
                     float* __restrict__ out) {
    __shared__ int hist[NUM_CLS];
    __shared__ float sred[4];
    __shared__ int scnt[4];
    const int tid = threadIdx.x;
    if (tid < NUM_CLS) hist[tid] = 0;
    __syncthreads();
    for (int i = tid; i < N_ROWS; i += 256) atomicAdd(&hist[labels[i]], 1);
    __syncthreads();

    float lsum = 0.f;
    int vcnt = 0;
    if (tid < 128) {
        const int i = blockIdx.x * 128 + tid;
        float p = 0.f, a = 0.f;
#pragma unroll
        for (int s = 0; s < NBLK; ++s) {
            p += ppos[(size_t)s * N_ROWS + i];
            a += pall[(size_t)s * N_ROWS + i];
        }
        const int cnt = hist[labels[i]] - 1;
        if (cnt > 0) {
            lsum = logf(a) - logf(p) + logf((float)cnt);   // >= 0 structurally
            vcnt = 1;
        }
    }
    const int lane = tid & 63, wid = tid >> 6;
#pragma unroll
    for (int d = 1; d < 64; d <<= 1) {
        lsum += __shfl_xor(lsum, d, 64);
        vcnt += __shfl_xor(vcnt, d, 64);
    }
    if (lane == 0) { sred[wid] = lsum; scnt[wid] = vcnt; }
    __syncthreads();
    if (tid == 0) {
        const double bs = (double)(sred[0] + sred[1] + sred[2] + sred[3]);
        const unsigned long long S = (unsigned long long)(bs * FIXSCALE + 0.5);
        const unsigned long long C = (unsigned long long)(scnt[0] + scnt[1] + scnt[2] + scnt[3]);
        atomicAdd(&acc[1], S);
        atomicAdd(&acc[2], C);
        __threadfence();
        const unsigned long long tk = atomicAdd(&acc[0], 1ULL);
        if (tk == (unsigned long long)(NBLK - 1)) {
            volatile unsigned long long* va = acc;
            const double St = (double)va[1];
            const double Ct = (double)va[2];
            out[0] = (float)(St / FIXSCALE / Ct);
        }
    }
}

extern "C" void kernel_launch(void* const* d_in, const int* in_sizes, int n_in,
                              void* d_out, int out_size, void* d_ws, size_t ws_size,
                              hipStream_t stream) {
    const float* emb   = (const float*)d_in[0];
    const int* labels  = (const int*)d_in[1];
    float* out         = (float*)d_out;
    char* ws           = (char*)d_ws;

    unsigned char* xq = (unsigned char*)ws;                      // 4 MB fp4 (x*64)
    float* ppos = (float*)(ws + (size_t)N_ROWS * ROWB);          // NBLK*N floats (2 MB)
    float* pall = ppos + (size_t)NBLK * N_ROWS;                  // NBLK*N floats (2 MB)
    unsigned long long* acc = (unsigned long long*)(pall + (size_t)NBLK * N_ROWS);

    norm_kernel<<<N_ROWS / 4, 256, 0, stream>>>(emb, (ushort*)xq, acc);
    simloss_kernel<<<GRID_K2, 256, 0, stream>>>(xq, labels, ppos, pall);
    finalize_kernel<<<NBLK, 256, 0, stream>>>(labels, ppos, pall, acc, out);
}

// Round 11
// 92.184 us; speedup vs baseline: 1.4570x; 1.0094x over previous
//
#include <hip/hip_runtime.h>
#include <hip/hip_bf16.h>

#define N_ROWS 8192
#define H_DIM  1024
#define NUM_CLS 64
#define BM 128
#define BN 128
#define ROWB (H_DIM / 2)                 // 512 bytes per fp4 row
#define NBLK (N_ROWS / BM)               // 64 panels
#define SCALE_E8M0 0x79797979            // 121 -> 2^-6 per operand (x stored *64)
#define FIXSCALE 16777216.0              // 2^24 fixed-point for deterministic sum
#define GRID_K2 (8 * 264)                // 8 XCD slots x 264 (32 no-op blocks)

typedef float f32x4 __attribute__((ext_vector_type(4)));
typedef int   i32x4 __attribute__((ext_vector_type(4)));
typedef int   i32x8 __attribute__((ext_vector_type(8)));

__device__ __forceinline__ float fast_exp2(float x) {
    float r;
    asm("v_exp_f32 %0, %1" : "=v"(r) : "v"(x));
    return r;
}

__device__ __forceinline__ void async_copy16(void* lds, const void* g) {
    __builtin_amdgcn_global_load_lds(
        (const __attribute__((address_space(1))) void*)g,
        (__attribute__((address_space(3))) void*)lds, 16, 0, 0);
}

// e2m1 encode of f (pre-scaled): codes 0..7 = {0,.5,1,1.5,2,3,4,6}, bit3 = sign
__device__ __forceinline__ unsigned enc_fp4(float f) {
    const float a = fabsf(f);
    unsigned c = (unsigned)(a > 0.25f) + (unsigned)(a > 0.75f) +
                 (unsigned)(a > 1.25f) + (unsigned)(a > 1.75f) +
                 (unsigned)(a > 2.5f)  + (unsigned)(a > 3.5f) +
                 (unsigned)(a > 5.0f);
    return c | ((__float_as_uint(f) >> 31) << 3);
}

// --- Kernel 1: row-normalize fp32 -> fp4 e2m1 (x*64); 4 rows/block ---
__global__ __launch_bounds__(256) void norm_kernel(const float* __restrict__ in,
                                                   ushort* __restrict__ out,
                                                   unsigned long long* __restrict__ acc) {
    if (blockIdx.x == 0 && threadIdx.x < 4) acc[threadIdx.x] = 0ULL;  // zero reducers
    const int row  = blockIdx.x * 4 + (threadIdx.x >> 6);
    const int lane = threadIdx.x & 63;
    const float4* src = reinterpret_cast<const float4*>(in + (size_t)row * H_DIM);
    float4 v[4];
    float ss = 0.f;
#pragma unroll
    for (int i = 0; i < 4; ++i) {
        v[i] = src[i * 64 + lane];                    // coalesced 16B/lane
        ss += v[i].x * v[i].x + v[i].y * v[i].y + v[i].z * v[i].z + v[i].w * v[i].w;
    }
#pragma unroll
    for (int d = 1; d < 64; d <<= 1) ss += __shfl_xor(ss, d, 64);
    const float inv = 64.0f / fmaxf(sqrtf(ss), 1e-12f);   // *64: fp4 resolution band
    ushort* op = out + (size_t)row * (ROWB / 2);          // 256 ushorts per row
#pragma unroll
    for (int i = 0; i < 4; ++i) {
        const unsigned b0 = enc_fp4(v[i].x * inv) | (enc_fp4(v[i].y * inv) << 4);
        const unsigned b1 = enc_fp4(v[i].z * inv) | (enc_fp4(v[i].w * inv) << 4);
        op[i * 64 + lane] = (ushort)(b0 | (b1 << 8));
    }
}

// 28 off-diagonal 8x8-panel super-tiles (a<b), packed a<<3|b, row-major
__device__ __constant__ unsigned char OFF_TBL[28] = {
    1, 2, 3, 4, 5, 6, 7,
    10, 11, 12, 13, 14, 15,
    19, 20, 21, 22, 23,
    28, 29, 30, 31,
    37, 38, 39,
    46, 47,
    55
};

// ---- Kernel 2: symmetric fused Gram + exp + masked row/col partials ----
// MX-fp4, double-buffered (2 x 16 KB, no occupancy cost), ONE barrier/step,
// swizzle key (row>>1)&3 -> 2-way (free) bank access on ds_read_b128.
__global__ __launch_bounds__(256, 4)
void simloss_kernel(const unsigned char* __restrict__ xq, const int* __restrict__ labels,
                    float* __restrict__ ppos, float* __restrict__ pall) {
    __shared__ __align__(16) unsigned char As[2][BM * 64];   // 2 x 8 KB
    __shared__ __align__(16) unsigned char Bs[2][BN * 64];   // 2 x 8 KB

    // ---- super-tile decode: xcd = blockIdx%8 owns a fixed tile list ----
    const int xcd = blockIdx.x & 7;
    const int n   = blockIdx.x >> 3;     // 0..263 within this XCD
    int I, J;
    if (xcd < 4) {                        // 4 off-diag tiles (256 blocks)
        if (n >= 256) return;
        const int t = OFF_TBL[xcd * 4 + (n >> 6)];
        I = (t >> 3) * 8 + ((n >> 3) & 7);
        J = (t & 7) * 8 + (n & 7);
    } else if (n < 192) {                 // 3 off-diag tiles
        const int t = OFF_TBL[16 + (xcd - 4) * 3 + (n >> 6)];
        I = (t >> 3) * 8 + ((n >> 3) & 7);
        J = (t & 7) * 8 + (n & 7);
    } else {                              // 2 diag tiles (36 blocks each)
        int n2 = n - 192;                 // 0..71
        const int D = (xcd - 4) * 2 + (n2 >= 36 ? 1 : 0);
        int t2 = (n2 >= 36) ? n2 - 36 : n2;
        int i = 0;
        while (t2 >= 8 - i) { t2 -= 8 - i; ++i; }
        I = D * 8 + i;
        J = D * 8 + i + t2;
    }
    const bool diag = (I == J);
    const int row0 = I * BM, col0 = J * BN;

    const int tid  = threadIdx.x;
    const int lane = tid & 63;
    const int wid  = tid >> 6;
    const int wr = wid >> 1, wc = wid & 1;
    const int l15 = lane & 15, lq = lane >> 4;

    f32x4 acc[4][4];
#pragma unroll
    for (int m = 0; m < 4; ++m)
#pragma unroll
        for (int n2 = 0; n2 < 4; ++n2) acc[m][n2] = (f32x4){0.f, 0.f, 0.f, 0.f};

    // read slot: logical chunk lq lives at phys slot lq ^ ((row>>1)&3);
    // row = wr*64 + m*16 + l15 -> key reduces to (l15>>1)&3.
    // Bank check: base = (row*16)%32 = {0,16} by parity; within each parity
    // class the key cycles 0..3 -> each (base,slot) pair = exactly 2 lanes (free).
    const int rslot = (lq ^ ((l15 >> 1) & 3)) * 16;
    const i32x4 z4 = {0, 0, 0, 0};

    // STAGE one K-step (64 B of K) into buffer b: 4 issues/thread, linear LDS
    // dest (wave-uniform base + lane*16); source chunk pre-swizzled (rule #21)
#define STAGE(b, k0b)                                                          \
    do {                                                                       \
        _Pragma("unroll")                                                      \
        for (int q = 0; q < 2; ++q) {                                          \
            const int seg = wid * 2 + q;                                       \
            const int row = seg * 16 + (lane >> 2);                            \
            const int ls  = (lane & 3) ^ ((row >> 1) & 3);                     \
            async_copy16(&As[b][seg * 1024],                                   \
                         &xq[(size_t)(row0 + row) * ROWB + (k0b) + ls * 16]);  \
            async_copy16(&Bs[b][seg * 1024],                                   \
                         &xq[(size_t)(col0 + row) * ROWB + (k0b) + ls * 16]);  \
        }                                                                      \
    } while (0)

    // prologue: stage step 0 into buf 0
    STAGE(0, 0);
    __syncthreads();                      // compiler drains vmcnt before barrier

    for (int s = 0; s < 8; ++s) {         // 8 K-steps x 128 elems
        const int buf = s & 1;
        if (s + 1 < 8) STAGE(buf ^ 1, (s + 1) * 64);   // prefetch, other buffer

        i32x8 av[4], bv[4];
#pragma unroll
        for (int m = 0; m < 4; ++m) {
            const i32x4 lo = *reinterpret_cast<const i32x4*>(
                &As[buf][(wr * 64 + m * 16 + l15) * 64 + rslot]);
            av[m] = __builtin_shufflevector(lo, z4, 0, 1, 2, 3, 4, 5, 6, 7);
        }
#pragma unroll
        for (int n2 = 0; n2 < 4; ++n2) {
            const i32x4 lo = *reinterpret_cast<const i32x4*>(
                &Bs[buf][(wc * 64 + n2 * 16 + l15) * 64 + rslot]);
            bv[n2] = __builtin_shufflevector(lo, z4, 0, 1, 2, 3, 4, 5, 6, 7);
        }
#pragma unroll
        for (int m = 0; m < 4; ++m)
#pragma unroll
            for (int n2 = 0; n2 < 4; ++n2)
                acc[m][n2] = __builtin_amdgcn_mfma_scale_f32_16x16x128_f8f6f4(
                    av[m], bv[n2], acc[m][n2],
                    4 /*cbsz: fp4 e2m1*/, 4 /*blgp: fp4 e2m1*/,
                    0, SCALE_E8M0, 0, SCALE_E8M0);

        // one barrier/step: drains this step's prefetch (issued ~500 cyc ago,
        // L2-hot via super-tile) AND guards buf reuse next iteration
        __syncthreads();
    }
#undef STAGE

    // ---- epilogue: exp + masked row sums AND column sums ----
    int lab_r[16];
#pragma unroll
    for (int m = 0; m < 4; ++m)
#pragma unroll
        for (int r = 0; r < 4; ++r)
            lab_r[m * 4 + r] = labels[row0 + wr * 64 + m * 16 + lq * 4 + r];

    float rs_pos[16], rs_all[16];
#pragma unroll
    for (int i = 0; i < 16; ++i) { rs_pos[i] = 0.f; rs_all[i] = 0.f; }
    float cs_pos[4], cs_all[4];
#pragma unroll
    for (int n2 = 0; n2 < 4; ++n2) { cs_pos[n2] = 0.f; cs_all[n2] = 0.f; }

#pragma unroll
    for (int n2 = 0; n2 < 4; ++n2) {
        const int colg = col0 + wc * 64 + n2 * 16 + l15;
        const int lab_c = labels[colg];
#pragma unroll
        for (int m = 0; m < 4; ++m) {
#pragma unroll
            for (int r = 0; r < 4; ++r) {
                const int rowg = row0 + wr * 64 + m * 16 + lq * 4 + r;
                const float e = fast_exp2(acc[m][n2][r] * 14.4269504088896340736f);
                const bool self = (rowg == colg);       // only possible when diag
                const bool pos  = (lab_c == lab_r[m * 4 + r]) && !self;
                const float ea = self ? 0.f : e;
                const float ep = pos ? e : 0.f;
                rs_all[m * 4 + r] += ea;
                rs_pos[m * 4 + r] += ep;
                cs_all[n2] += ea;
                cs_pos[n2] += ep;
            }
        }
    }

#pragma unroll
    for (int i = 0; i < 16; ++i) {
#pragma unroll
        for (int d = 1; d < 16; d <<= 1) {
            rs_pos[i] += __shfl_xor(rs_pos[i], d, 64);
            rs_all[i] += __shfl_xor(rs_all[i], d, 64);
        }
    }
#pragma unroll
    for (int n2 = 0; n2 < 4; ++n2) {
#pragma unroll
        for (int d = 16; d < 64; d <<= 1) {
            cs_pos[n2] += __shfl_xor(cs_pos[n2], d, 64);
            cs_all[n2] += __shfl_xor(cs_all[n2], d, 64);
        }
    }

    __syncthreads();                       // all LDS fragment reads done
    float* sc = (float*)&As[0][0];
    float* rowpos = sc;                    // [2][128] indexed [wc][localrow]
    float* rowall = sc + 256;
    float* colpos = sc + 512;              // [2][128] indexed [wr][localcol]
    float* colall = sc + 768;              // 4 KB total
    if (l15 == 0) {
#pragma unroll
        for (int i = 0; i < 16; ++i) {
            const int m = i >> 2, r = i & 3;
            const int lr = wr * 64 + m * 16 + lq * 4 + r;
            rowpos[wc * 128 + lr] = rs_pos[i];
            rowall[wc * 128 + lr] = rs_all[i];
        }
    }
    if (lq == 0 && !diag) {
#pragma unroll
        for (int n2 = 0; n2 < 4; ++n2) {
            const int lc = wc * 64 + n2 * 16 + l15;
            colpos[wr * 128 + lc] = cs_pos[n2];
            colall[wr * 128 + lc] = cs_all[n2];
        }
    }
    __syncthreads();

    // partial-slot scheme: row-side -> slot J, col-side -> slot I (exactly once)
    if (tid < 128) {
        const float rp = rowpos[tid] + rowpos[128 + tid];
        const float ra = rowall[tid] + rowall[128 + tid];
        ppos[(size_t)J * N_ROWS + row0 + tid] = rp;
        pall[(size_t)J * N_ROWS + row0 + tid] = ra;
    } else if (!diag) {
        const int t2 = tid - 128;
        const float cp = colpos[t2] + colpos[128 + t2];
        const float ca = colall[t2] + colall[128 + t2];
        ppos[(size_t)I * N_ROWS + col0 + t2] = cp;
        pall[(size_t)I * N_ROWS + col0 + t2] = ca;
    }
}

// ---- Kernel 3: fused finalize (deterministic int64 fixed-point + ticket) ----
__global__ __launch_bounds__(256)
void finalize_kernel(const int* __restrict__ labels, const float* __restrict__ ppos,
                     const float* __restrict__ pall, unsigned long long* __restrict__ acc,
                     float* __restrict__ out) {
    __shared__ int hist[NUM_CLS];
    __shared__ float sred[4];
    __shared__ int scnt[4];
    const int tid = threadIdx.x;
    if (tid < NUM_CLS) hist[tid] = 0;
    __syncthreads();
    for (int i = tid; i < N_ROWS; i += 256) atomicAdd(&hist[labels[i]], 1);
    __syncthreads();

    float lsum = 0.f;
    int vcnt = 0;
    if (tid < 128) {
        const int i = blockIdx.x * 128 + tid;
        float p = 0.f, a = 0.f;
#pragma unroll
        for (int s = 0; s < NBLK; ++s) {
            p += ppos[(size_t)s * N_ROWS + i];
            a += pall[(size_t)s * N_ROWS + i];
        }
        const int cnt = hist[labels[i]] - 1;
        if (cnt > 0) {
            lsum = logf(a) - logf(p) + logf((float)cnt);   // >= 0 structurally
            vcnt = 1;
        }
    }
    const int lane = tid & 63, wid = tid >> 6;
#pragma unroll
    for (int d = 1; d < 64; d <<= 1) {
        lsum += __shfl_xor(lsum, d, 64);
        vcnt += __shfl_xor(vcnt, d, 64);
    }
    if (lane == 0) { sred[wid] = lsum; scnt[wid] = vcnt; }
    __syncthreads();
    if (tid == 0) {
        const double bs = (double)(sred[0] + sred[1] + sred[2] + sred[3]);
        const unsigned long long S = (unsigned long long)(bs * FIXSCALE + 0.5);
        const unsigned long long C = (unsigned long long)(scnt[0] + scnt[1] + scnt[2] + scnt[3]);
        atomicAdd(&acc[1], S);
        atomicAdd(&acc[2], C);
        __threadfence();
        const unsigned long long tk = atomicAdd(&acc[0], 1ULL);
        if (tk == (unsigned long long)(NBLK - 1)) {
            volatile unsigned long long* va = acc;
            const double St = (double)va[1];
            const double Ct = (double)va[2];
            out[0] = (float)(St / FIXSCALE / Ct);
        }
    }
}

extern "C" void kernel_launch(void* const* d_in, const int* in_sizes, int n_in,
                              void* d_out, int out_size, void* d_ws, size_t ws_size,
                              hipStream_t stream) {
    const float* emb   = (const float*)d_in[0];
    const int* labels  = (const int*)d_in[1];
    float* out         = (float*)d_out;
    char* ws           = (char*)d_ws;

    unsigned char* xq = (unsigned char*)ws;                      // 4 MB fp4 (x*64)
    float* ppos = (float*)(ws + (size_t)N_ROWS * ROWB);          // NBLK*N floats (2 MB)
    float* pall = ppos + (size_t)NBLK * N_ROWS;                  // NBLK*N floats (2 MB)
    unsigned long long* acc = (unsigned long long*)(pall + (size_t)NBLK * N_ROWS);

    norm_kernel<<<N_ROWS / 4, 256, 0, stream>>>(emb, (ushort*)xq, acc);
    simloss_kernel<<<GRID_K2, 256, 0, stream>>>(xq, labels, ppos, pall);
    finalize_kernel<<<NBLK, 256, 0, stream>>>(labels, ppos, pall, acc, out);
}